// Round 4
// baseline (647.869 us; speedup 1.0000x reference)
//
#include <hip/hip_runtime.h>
#include <hip/hip_bf16.h>
#include <stdint.h>

#define M_DIM 16384   // B*S = 4*4096
#define N_DIM 4096    // OUT
#define K_DIM 4096    // IN
#define NT    (K_DIM / 64)   // 64 K-tiles of BK=64

typedef float f32x4 __attribute__((ext_vector_type(4)));
typedef short bf16x8 __attribute__((ext_vector_type(8)));
typedef unsigned short u16;

__device__ __forceinline__ unsigned short f32_to_bf16(float f) {
    union { float f; uint32_t u; } v; v.f = f;
    uint32_t u = v.u;
    uint32_t r = (u + 0x7FFFu + ((u >> 16) & 1u)) >> 16;   // RNE
    return (unsigned short)r;
}

__device__ __forceinline__ void gload16(const void* g, void* l) {
    __builtin_amdgcn_global_load_lds(
        (const __attribute__((address_space(1))) void*)g,
        (__attribute__((address_space(3))) void*)l,
        16, 0, 0);
}

// ---------------------------------------------------------------------------
// Kernel 1: Weff[o][i] = bf16( W0[o][i] + 0.25 * w1[o>>6][i>>6] * w2[o&63][i&63] )
// ---------------------------------------------------------------------------
__global__ void build_weff(const float* __restrict__ W0,
                           const float* __restrict__ w1,
                           const float* __restrict__ w2a,
                           const float* __restrict__ w2b,
                           u16* __restrict__ Weff) {
    long idx = (long)blockIdx.x * 256 + threadIdx.x;   // over N*K/4
    long e0 = idx * 4;
    int o  = (int)(e0 >> 12);
    int i0 = (int)(e0 & 4095);
    int r  = o & 63;
    float a0 = w2a[r * 4 + 0], a1 = w2a[r * 4 + 1];
    float a2 = w2a[r * 4 + 2], a3 = w2a[r * 4 + 3];
    float w1v = w1[(o >> 6) * 64 + (i0 >> 6)] * 0.25f;
    float4 w0 = *(const float4*)(W0 + e0);
    const float* w0p = (const float*)&w0;
    unsigned short outp[4];
#pragma unroll
    for (int j = 0; j < 4; ++j) {
        int c = (i0 + j) & 63;
        float w2 = a0 * w2b[0 * 64 + c] + a1 * w2b[1 * 64 + c]
                 + a2 * w2b[2 * 64 + c] + a3 * w2b[3 * 64 + c];
        outp[j] = f32_to_bf16(w0p[j] + w1v * w2);
    }
    *(ushort4*)(Weff + e0) = make_ushort4(outp[0], outp[1], outp[2], outp[3]);
}

// ---------------------------------------------------------------------------
// Kernel 2: x f32 -> bf16
// ---------------------------------------------------------------------------
__global__ void cvt_x(const float* __restrict__ x, u16* __restrict__ xb) {
    long idx = (long)blockIdx.x * 256 + threadIdx.x;   // over M*K/8
    long e0 = idx * 8;
    float4 v0 = *(const float4*)(x + e0);
    float4 v1 = *(const float4*)(x + e0 + 4);
    union { unsigned short s[8]; int4 v; } o;
    const float* p0 = (const float*)&v0;
    const float* p1 = (const float*)&v1;
#pragma unroll
    for (int j = 0; j < 4; ++j) o.s[j]     = f32_to_bf16(p0[j]);
#pragma unroll
    for (int j = 0; j < 4; ++j) o.s[4 + j] = f32_to_bf16(p1[j]);
    *(int4*)(xb + e0) = o.v;
}

// ---------------------------------------------------------------------------
// Kernel 3: 256x256 tile, BK=64, 8 waves (2Mx4N), 8-phase schedule with
// REGISTER DOUBLE-BUFFERED fragments: each phase issues next phase's
// ds_reads into the alternate register set; MFMA consumes previous set.
// Compiler inserts counted lgkmcnt (waits only on older reads).
// vmcnt(4) gates at P3/P7 (after MFMA, before end barrier).
// C[m][o] = sum_k A[m][k]*B[o][k] + bias[o]
// ---------------------------------------------------------------------------
__global__ __launch_bounds__(512, 2) void gemm_8p(
        const u16* __restrict__ A,    // M x K bf16
        const u16* __restrict__ Bm,   // N x K bf16 (B^T)
        const float* __restrict__ bias,
        float* __restrict__ C) {
    // [buf][kslice][256 rows][32 cols] bf16, 16KB per (buf,kslice) region
    __shared__ __align__(16) u16 ldsA[2][2][8192];
    __shared__ __align__(16) u16 ldsB[2][2][8192];

    const int tid = threadIdx.x;
    const int bid = blockIdx.x;
    // bijective XCD swizzle (nwg = 1024, %8==0)
    const int swz = (bid & 7) * 128 + (bid >> 3);
    const int tm = swz >> 4;          // 64 M-tiles
    const int tn = swz & 15;          // 16 N-tiles
    const int mBase = tm * 256;
    const int nBase = tn * 256;

    const int lane = tid & 63;
    const int wave = tid >> 6;
    const int wr = wave >> 2;         // 0..1  (M half)
    const int wc = wave & 3;          // 0..3  (N quarter)

    // ---- staging (write side): linear LDS dest, inverse-swizzled source ----
    const int srow = tid >> 2;                        // 0..127
    const int slog = (tid & 3) ^ ((srow >> 1) & 3);   // logical 16B slot
    const u16* aS0 = A  + (size_t)(mBase + srow)       * K_DIM + slog * 8;
    const u16* aS1 = A  + (size_t)(mBase + srow + 128) * K_DIM + slog * 8;
    const u16* bS0 = Bm + (size_t)(nBase + srow)       * K_DIM + slog * 8;
    const u16* bS1 = Bm + (size_t)(nBase + srow + 128) * K_DIM + slog * 8;

#define STAGE_A(buf, t, ks) do { const size_t _k = (size_t)(t) * 64 + (ks) * 32; \
        gload16(aS0 + _k, &ldsA[buf][ks][tid * 8]);                              \
        gload16(aS1 + _k, &ldsA[buf][ks][4096 + tid * 8]); } while (0)
#define STAGE_B(buf, t, ks) do { const size_t _k = (size_t)(t) * 64 + (ks) * 32; \
        gload16(bS0 + _k, &ldsB[buf][ks][tid * 8]);                              \
        gload16(bS1 + _k, &ldsB[buf][ks][4096 + tid * 8]); } while (0)

    // ---- fragment read bases (swizzled) ----
    const int rl = lane & 15, cbk = lane >> 4;        // row-in-frag, k-block
    const int sslot = cbk ^ ((rl >> 1) & 3);
    const int aRd = (wr * 128 + rl) * 32 + sslot * 8;  // ushort offset
    const int bRd = (wc * 64  + rl) * 32 + sslot * 8;

#define RD_A(buf, ks, m) (*(const bf16x8*)&ldsA[buf][ks][aRd + (m) * 512])
#define RD_B(buf, ks, n) (*(const bf16x8*)&ldsB[buf][ks][bRd + (n) * 512])

    f32x4 acc[8][4] = {};
    // double-buffered operand sets (all statically named — rule #20)
    bf16x8 aA0, aA1, aA2, aA3;   // A lo-half (m0..3)  -> acc rows 0..3
    bf16x8 aB0, aB1, aB2, aB3;   // A hi-half (m4..7)  -> acc rows 4..7
    bf16x8 bX0, bX1, bX2, bX3;   // B ks=0 set
    bf16x8 bY0, bY1, bY2, bY3;   // B ks=1 set

#define MFMA16(A0_,A1_,A2_,A3_,B0_,B1_,B2_,B3_,mh)                                      \
    acc[(mh)*4+0][0] = __builtin_amdgcn_mfma_f32_16x16x32_bf16(A0_, B0_, acc[(mh)*4+0][0], 0, 0, 0); \
    acc[(mh)*4+0][1] = __builtin_amdgcn_mfma_f32_16x16x32_bf16(A0_, B1_, acc[(mh)*4+0][1], 0, 0, 0); \
    acc[(mh)*4+0][2] = __builtin_amdgcn_mfma_f32_16x16x32_bf16(A0_, B2_, acc[(mh)*4+0][2], 0, 0, 0); \
    acc[(mh)*4+0][3] = __builtin_amdgcn_mfma_f32_16x16x32_bf16(A0_, B3_, acc[(mh)*4+0][3], 0, 0, 0); \
    acc[(mh)*4+1][0] = __builtin_amdgcn_mfma_f32_16x16x32_bf16(A1_, B0_, acc[(mh)*4+1][0], 0, 0, 0); \
    acc[(mh)*4+1][1] = __builtin_amdgcn_mfma_f32_16x16x32_bf16(A1_, B1_, acc[(mh)*4+1][1], 0, 0, 0); \
    acc[(mh)*4+1][2] = __builtin_amdgcn_mfma_f32_16x16x32_bf16(A1_, B2_, acc[(mh)*4+1][2], 0, 0, 0); \
    acc[(mh)*4+1][3] = __builtin_amdgcn_mfma_f32_16x16x32_bf16(A1_, B3_, acc[(mh)*4+1][3], 0, 0, 0); \
    acc[(mh)*4+2][0] = __builtin_amdgcn_mfma_f32_16x16x32_bf16(A2_, B0_, acc[(mh)*4+2][0], 0, 0, 0); \
    acc[(mh)*4+2][1] = __builtin_amdgcn_mfma_f32_16x16x32_bf16(A2_, B1_, acc[(mh)*4+2][1], 0, 0, 0); \
    acc[(mh)*4+2][2] = __builtin_amdgcn_mfma_f32_16x16x32_bf16(A2_, B2_, acc[(mh)*4+2][2], 0, 0, 0); \
    acc[(mh)*4+2][3] = __builtin_amdgcn_mfma_f32_16x16x32_bf16(A2_, B3_, acc[(mh)*4+2][3], 0, 0, 0); \
    acc[(mh)*4+3][0] = __builtin_amdgcn_mfma_f32_16x16x32_bf16(A3_, B0_, acc[(mh)*4+3][0], 0, 0, 0); \
    acc[(mh)*4+3][1] = __builtin_amdgcn_mfma_f32_16x16x32_bf16(A3_, B1_, acc[(mh)*4+3][1], 0, 0, 0); \
    acc[(mh)*4+3][2] = __builtin_amdgcn_mfma_f32_16x16x32_bf16(A3_, B2_, acc[(mh)*4+3][2], 0, 0, 0); \
    acc[(mh)*4+3][3] = __builtin_amdgcn_mfma_f32_16x16x32_bf16(A3_, B3_, acc[(mh)*4+3][3], 0, 0, 0);

#define RD_BSET(set, buf, ks)                                   \
    set##0 = RD_B(buf, ks, 0); set##1 = RD_B(buf, ks, 1);       \
    set##2 = RD_B(buf, ks, 2); set##3 = RD_B(buf, ks, 3);
#define RD_ALO(buf, ks)                                         \
    aA0 = RD_A(buf, ks, 0); aA1 = RD_A(buf, ks, 1);             \
    aA2 = RD_A(buf, ks, 2); aA3 = RD_A(buf, ks, 3);
#define RD_AHI(buf, ks)                                         \
    aB0 = RD_A(buf, ks, 4); aB1 = RD_A(buf, ks, 5);             \
    aB2 = RD_A(buf, ks, 6); aB3 = RD_A(buf, ks, 7);

#define PH_END() do { __builtin_amdgcn_sched_barrier(0);        \
                      __builtin_amdgcn_s_barrier(); } while (0)

    // ---- prologue: tile0 -> buf0 (8 loads), tile1 B0/A0/B1 -> buf1 (6) ----
    STAGE_B(0, 0, 0); STAGE_A(0, 0, 0); STAGE_B(0, 0, 1); STAGE_A(0, 0, 1);
    STAGE_B(1, 1, 0); STAGE_A(1, 1, 0); STAGE_B(1, 1, 1);
    asm volatile("s_waitcnt vmcnt(6)" ::: "memory");   // buf0/tile0 complete
    __builtin_amdgcn_s_barrier();
    // pre-loop reads for P1: B(buf0,ks0)->bX, A lo(buf0,ks0)->aA
    RD_BSET(bX, 0, 0)
    RD_ALO(0, 0)

    // ---- main loop: 32 iterations x 2 K-tiles, 8 phases each ----
    for (int it = 0; it < NT / 2; ++it) {
        const int t1 = 2 * it + 1;
        const int t2 = (2 * it + 2 < NT) ? 2 * it + 2 : NT - 1;
        const int t3 = (2 * it + 3 < NT) ? 2 * it + 3 : NT - 1;

        // P1: MFMA(aA,bX,mh0)   reads->P2: A hi (buf0,ks0)
        STAGE_A(1, t1, 1);
        RD_AHI(0, 0)
        __builtin_amdgcn_s_setprio(1);
        MFMA16(aA0, aA1, aA2, aA3, bX0, bX1, bX2, bX3, 0)
        __builtin_amdgcn_s_setprio(0);
        PH_END();

        // P2: MFMA(aB,bX,mh1)   reads->P3: B(buf0,ks1)->bY, A lo(buf0,ks1)
        STAGE_B(0, t2, 0);
        RD_BSET(bY, 0, 1)
        RD_ALO(0, 1)
        __builtin_amdgcn_s_setprio(1);
        MFMA16(aB0, aB1, aB2, aB3, bX0, bX1, bX2, bX3, 1)
        __builtin_amdgcn_s_setprio(0);
        PH_END();

        // P3: MFMA(aA,bY,mh0)   reads->P4: A hi(buf0,ks1); gate buf1/tile-odd
        STAGE_A(0, t2, 0);
        RD_AHI(0, 1)
        __builtin_amdgcn_s_setprio(1);
        MFMA16(aA0, aA1, aA2, aA3, bY0, bY1, bY2, bY3, 0)
        __builtin_amdgcn_s_setprio(0);
        asm volatile("s_waitcnt vmcnt(4)" ::: "memory");   // buf1 tile-odd landed
        PH_END();

        // P4: MFMA(aB,bY,mh1)   reads->P5: B(buf1,ks0)->bX, A lo(buf1,ks0)
        STAGE_B(0, t2, 1);
        RD_BSET(bX, 1, 0)
        RD_ALO(1, 0)
        __builtin_amdgcn_s_setprio(1);
        MFMA16(aB0, aB1, aB2, aB3, bY0, bY1, bY2, bY3, 1)
        __builtin_amdgcn_s_setprio(0);
        PH_END();

        // P5: MFMA(aA,bX,mh0)   reads->P6: A hi(buf1,ks0)
        STAGE_A(0, t2, 1);
        RD_AHI(1, 0)
        __builtin_amdgcn_s_setprio(1);
        MFMA16(aA0, aA1, aA2, aA3, bX0, bX1, bX2, bX3, 0)
        __builtin_amdgcn_s_setprio(0);
        PH_END();

        // P6: MFMA(aB,bX,mh1)   reads->P7: B(buf1,ks1)->bY, A lo(buf1,ks1)
        STAGE_B(1, t3, 0);
        RD_BSET(bY, 1, 1)
        RD_ALO(1, 1)
        __builtin_amdgcn_s_setprio(1);
        MFMA16(aB0, aB1, aB2, aB3, bX0, bX1, bX2, bX3, 1)
        __builtin_amdgcn_s_setprio(0);
        PH_END();

        // P7: MFMA(aA,bY,mh0)   reads->P8: A hi(buf1,ks1); gate buf0/tile-even
        STAGE_A(1, t3, 0);
        RD_AHI(1, 1)
        __builtin_amdgcn_s_setprio(1);
        MFMA16(aA0, aA1, aA2, aA3, bY0, bY1, bY2, bY3, 0)
        __builtin_amdgcn_s_setprio(0);
        asm volatile("s_waitcnt vmcnt(4)" ::: "memory");   // buf0 tile-even landed
        PH_END();

        // P8: MFMA(aB,bY,mh1)   reads->P1': B(buf0',ks0)->bX, A lo(buf0',ks0)
        STAGE_B(1, t3, 1);
        RD_BSET(bX, 0, 0)
        RD_ALO(0, 0)
        __builtin_amdgcn_s_setprio(1);
        MFMA16(aB0, aB1, aB2, aB3, bY0, bY1, bY2, bY3, 1)
        __builtin_amdgcn_s_setprio(0);
        PH_END();
    }
    asm volatile("s_waitcnt vmcnt(0) lgkmcnt(0)" ::: "memory");

    // ---- epilogue: C/D layout col=lane&15, row=(lane>>4)*4+j ----
#pragma unroll
    for (int n = 0; n < 4; ++n) {
        const int col = nBase + wc * 64 + n * 16 + rl;
        const float bv = bias[col];
#pragma unroll
        for (int m = 0; m < 8; ++m) {
            const int row = mBase + wr * 128 + m * 16 + cbk * 4;
#pragma unroll
            for (int j = 0; j < 4; ++j)
                C[(size_t)(row + j) * N_DIM + col] = acc[m][n][j] + bv;
        }
    }
#undef STAGE_A
#undef STAGE_B
#undef RD_A
#undef RD_B
#undef RD_BSET
#undef RD_ALO
#undef RD_AHI
#undef MFMA16
#undef PH_END
}

// ---------------------------------------------------------------------------
// Fallback (only if ws_size too small): correct but slow
// ---------------------------------------------------------------------------
__global__ void naive_fallback(const float* __restrict__ x,
                               const float* __restrict__ W0,
                               const float* __restrict__ b,
                               const float* __restrict__ w1,
                               const float* __restrict__ w2a,
                               const float* __restrict__ w2b,
                               float* __restrict__ out) {
    __shared__ float w2s[64 * 64];
    for (int t = threadIdx.x; t < 4096; t += blockDim.x) {
        int rr = t >> 6, cc = t & 63;
        float s = 0.f;
        for (int k = 0; k < 4; ++k) s += w2a[rr * 4 + k] * w2b[k * 64 + cc];
        w2s[t] = s * 0.25f;
    }
    __syncthreads();
    long idx = (long)blockIdx.x * blockDim.x + threadIdx.x;
    int m = (int)(idx >> 12);
    int o = (int)(idx & 4095);
    const float* xr = x + (long)m * K_DIM;
    const float* wrp = W0 + (long)o * K_DIM;
    int ob = (o >> 6) * 64, orr = (o & 63) * 64;
    float acc = 0.f;
    for (int i = 0; i < K_DIM; ++i) {
        float w = wrp[i] + w1[ob + (i >> 6)] * w2s[orr + (i & 63)];
        acc += xr[i] * w;
    }
    out[idx] = acc + b[o];
}

extern "C" void kernel_launch(void* const* d_in, const int* in_sizes, int n_in,
                              void* d_out, int out_size, void* d_ws, size_t ws_size,
                              hipStream_t stream) {
    const float* x   = (const float*)d_in[0];
    const float* W0  = (const float*)d_in[1];
    const float* b   = (const float*)d_in[2];
    const float* w1  = (const float*)d_in[3];
    const float* w2a = (const float*)d_in[4];
    const float* w2b = (const float*)d_in[5];
    float* out = (float*)d_out;

    const size_t xb_bytes = (size_t)M_DIM * K_DIM * 2;   // 128 MB
    const size_t wf_bytes = (size_t)N_DIM * K_DIM * 2;   // 32 MB

    if (ws_size >= xb_bytes + wf_bytes) {
        u16* xb = (u16*)d_ws;
        u16* wf = (u16*)((char*)d_ws + xb_bytes);
        build_weff<<<(N_DIM * (long)K_DIM) / 4 / 256, 256, 0, stream>>>(W0, w1, w2a, w2b, wf);
        cvt_x<<<((long)M_DIM * K_DIM) / 8 / 256, 256, 0, stream>>>(x, xb);
        gemm_8p<<<(M_DIM / 256) * (N_DIM / 256), 512, 0, stream>>>(xb, wf, b, out);
    } else {
        naive_fallback<<<((long)M_DIM * N_DIM) / 256, 256, 0, stream>>>(
            x, W0, b, w1, w2a, w2b, out);
    }
}